// Round 1
// baseline (74.956 us; speedup 1.0000x reference)
//
#include <hip/hip_runtime.h>

// Problem constants
#define B_    8
#define C_    512
#define T_    512
#define O_    512
#define K_    65
#define PAD_  32

// Tiling
#define O_TILE 32          // o per block
#define T_TILE 128         // t per block
#define J_     8           // o per wave (wave-uniform weight rows)
#define NW     4           // waves per block (256 threads)
#define ROWS   (O_TILE + 2 * PAD_)   // 96 x-tile rows
#define NR     (J_ + 2 * PAD_)       // 72 sliding steps per wave
#define YPITCH 36          // y-tile LDS pitch (16B-aligned rows, bank-rotating)

// Transformed weights: Wt[og][r][j] = W[og*8+j][r-j] (0 outside band)
#define NOG       (O_ / J_)             // 64
#define WT_ELEMS  (NOG * NR * J_)       // 36864 floats = 147456 B

__global__ __launch_bounds__(256) void wt_prep(const float* __restrict__ w,
                                               float* __restrict__ wt) {
    int e = blockIdx.x * 256 + threadIdx.x;
    if (e >= WT_ELEMS) return;
    int og  = e / (NR * J_);
    int rem = e % (NR * J_);
    int r   = rem / J_;
    int j   = rem % J_;
    int k   = r - j;
    float v = 0.0f;
    if (k >= 0 && k < K_) v = w[(og * J_ + j) * K_ + k];
    wt[e] = v;
}

template <bool USE_WT>
__global__ __launch_bounds__(256) void conv_main(const float* __restrict__ x,
                                                 const float* __restrict__ w,
                                                 const float* __restrict__ bias,
                                                 const float* __restrict__ wt,
                                                 float* __restrict__ out) {
    __shared__ float smem[ROWS * T_TILE];   // 96*128 floats = 48 KB (reused for y-tile)

    const int tid = threadIdx.x;
    const int bid = blockIdx.x;             // 512 blocks: b(8) x ob(16) x tb(4)
    const int b   = bid >> 6;
    const int rem = bid & 63;
    const int ob  = rem >> 2;               // [0,16)
    const int tb  = rem & 3;                // [0,4)
    const int t0  = tb * T_TILE;
    const int c_base = ob * O_TILE - PAD_;

    // ---- Stage x tile: rows c_base..c_base+95, cols t0..t0+127, zero-padded ----
    {
        const float* xb = x + (size_t)b * (C_ * T_);
        const int l32 = tid & 31;           // 32 lanes * float4 = 128 floats/row
        const int rg  = tid >> 5;           // 8 rows per pass
        #pragma unroll
        for (int rr = 0; rr < ROWS / 8; ++rr) {   // 12 passes
            const int row = rr * 8 + rg;
            const int c   = c_base + row;
            float4 v = make_float4(0.f, 0.f, 0.f, 0.f);
            if (c >= 0 && c < C_)
                v = *(const float4*)(xb + c * T_ + t0 + l32 * 4);
            *(float4*)(&smem[row * T_TILE + l32 * 4]) = v;
        }
    }
    __syncthreads();

    // ---- Compute: wave wu owns o = obase..obase+7, lanes span t (2 each) ----
    const int lane  = tid & 63;
    const int wu    = __builtin_amdgcn_readfirstlane(tid >> 6);  // wave-uniform
    const int og    = ob * NW + wu;          // [0,64)
    const int obase = og * J_;

    float2 acc[J_];
    #pragma unroll
    for (int j = 0; j < J_; ++j) {
        const float bj = bias[obase + j];    // uniform -> scalar load
        acc[j] = make_float2(bj, bj);
    }

    const int tl = lane * 2;                 // t_local
    const float* wt_base = wt + (size_t)og * (NR * J_);

    for (int r = 0; r < NR; ++r) {           // 72 sliding steps
        const float2 xv = *(const float2*)(&smem[(wu * J_ + r) * T_TILE + tl]);
        float w8[J_];
        if (USE_WT) {
            const float4 wa = *(const float4*)(wt_base + r * J_);
            const float4 wb = *(const float4*)(wt_base + r * J_ + 4);
            w8[0] = wa.x; w8[1] = wa.y; w8[2] = wa.z; w8[3] = wa.w;
            w8[4] = wb.x; w8[5] = wb.y; w8[6] = wb.z; w8[7] = wb.w;
        } else {
            #pragma unroll
            for (int j = 0; j < J_; ++j) {
                const int k = r - j;
                w8[j] = (k >= 0 && k < K_) ? w[(obase + j) * K_ + k] : 0.f;
            }
        }
        #pragma unroll
        for (int j = 0; j < J_; ++j) {
            acc[j].x += w8[j] * xv.x;
            acc[j].y += w8[j] * xv.y;
        }
    }

    __syncthreads();   // x tile dead; reuse smem as y tile [t][o] pitch YPITCH

    // ---- Transpose through LDS ----
    {
        const int olb = wu * J_;
        #pragma unroll
        for (int j = 0; j < J_; ++j) {
            smem[tl * YPITCH + olb + j]       = acc[j].x;
            smem[(tl + 1) * YPITCH + olb + j] = acc[j].y;
        }
    }
    __syncthreads();

    // ---- Coalesced global store: 128 t-rows x 32 o (float4 runs) ----
    {
        float* ob_out = out + (size_t)b * (T_ * O_) + (size_t)t0 * O_ + ob * O_TILE;
        const int ol   = (tid & 7) * 4;      // [0,32) step 4
        const int trow = tid >> 3;           // [0,32)
        #pragma unroll
        for (int p = 0; p < 4; ++p) {
            const int t_local = p * 32 + trow;
            const float4 v = *(const float4*)(&smem[t_local * YPITCH + ol]);
            *(float4*)(ob_out + (size_t)t_local * O_ + ol) = v;
        }
    }
}

extern "C" void kernel_launch(void* const* d_in, const int* in_sizes, int n_in,
                              void* d_out, int out_size, void* d_ws, size_t ws_size,
                              hipStream_t stream) {
    const float* x    = (const float*)d_in[0];
    const float* w    = (const float*)d_in[1];
    const float* bias = (const float*)d_in[2];
    float* out = (float*)d_out;
    float* wt  = (float*)d_ws;

    const int nblocks = B_ * (O_ / O_TILE) * (T_ / T_TILE);   // 512

    if (ws_size >= (size_t)WT_ELEMS * sizeof(float)) {
        wt_prep<<<(WT_ELEMS + 255) / 256, 256, 0, stream>>>(w, wt);
        conv_main<true><<<nblocks, 256, 0, stream>>>(x, w, bias, wt, out);
    } else {
        conv_main<false><<<nblocks, 256, 0, stream>>>(x, w, bias, w, out);
    }
}